// Round 7
// baseline (2134.370 us; speedup 1.0000x reference)
//
#include <hip/hip_runtime.h>

typedef short short8 __attribute__((ext_vector_type(8)));
typedef float f4 __attribute__((ext_vector_type(4)));
typedef int i4 __attribute__((ext_vector_type(4)));
typedef _Float16 half8 __attribute__((ext_vector_type(8)));
typedef _Float16 h2 __attribute__((ext_vector_type(2)));

#define HD 256
#define ED 300
#define EP 320
#define TH 768
#define NS 1024
#define LW 64
#define SH 4.5f

__device__ __forceinline__ unsigned short f2bf(float f) {
    unsigned int u = __float_as_uint(f);
    u = (u + 0x7FFFu + ((u >> 16) & 1u)) >> 16;
    return (unsigned short)u;
}
__device__ __forceinline__ float bf2f(unsigned short s) {
    return __uint_as_float(((unsigned int)s) << 16);
}
__device__ __forceinline__ float sigm(float x) {
    return __builtin_amdgcn_rcpf(1.f + __expf(-x));
}
__device__ __forceinline__ float tanh_(float x) {
    x = fminf(fmaxf(x, -15.f), 15.f);
    return 1.f - 2.f * __builtin_amdgcn_rcpf(1.f + __expf(2.f * x));
}
__device__ __forceinline__ unsigned int pack_h2(float a, float b) {
    h2 p; p.x = (_Float16)a; p.y = (_Float16)b;
    return __builtin_bit_cast(unsigned int, p);
}

__device__ __forceinline__ void load8bf(const unsigned short* p, float* o) {
    uint4 a = *(const uint4*)p;
    o[0] = bf2f((unsigned short)(a.x & 0xffff)); o[1] = bf2f((unsigned short)(a.x >> 16));
    o[2] = bf2f((unsigned short)(a.y & 0xffff)); o[3] = bf2f((unsigned short)(a.y >> 16));
    o[4] = bf2f((unsigned short)(a.z & 0xffff)); o[5] = bf2f((unsigned short)(a.z >> 16));
    o[6] = bf2f((unsigned short)(a.w & 0xffff)); o[7] = bf2f((unsigned short)(a.w >> 16));
}
__device__ __forceinline__ void ubf4(uint2 a, float* o) {
    o[0] = bf2f((unsigned short)(a.x & 0xffff)); o[1] = bf2f((unsigned short)(a.x >> 16));
    o[2] = bf2f((unsigned short)(a.y & 0xffff)); o[3] = bf2f((unsigned short)(a.y >> 16));
}

// ---------------- prep: weight conversions, i8 quantization, Dq table, topic vector ----------------
__global__ void k_prep(const float* __restrict__ W, const float* __restrict__ U,
                       const float* __restrict__ Wih, const float* __restrict__ Whh,
                       const float* __restrict__ q, const float* __restrict__ Dm,
                       const float* __restrict__ DT, const float* __restrict__ mlpW,
                       const float* __restrict__ mlpb,
                       const float* __restrict__ bih, const float* __restrict__ bhh,
                       unsigned short* __restrict__ Wb, _Float16* __restrict__ Uh,
                       _Float16* __restrict__ Wihh, _Float16* __restrict__ Whhh,
                       signed char* __restrict__ Wq, float* __restrict__ rowscale,
                       float* __restrict__ bias2,
                       float* __restrict__ Dq, float* __restrict__ tv) {
    __shared__ float smax[4];
    int bid = blockIdx.x, tid = threadIdx.x;
    if (bid < 768) {
        int r = bid;
        for (int j = tid; j < EP; j += 256)
            Wb[r * EP + j] = (j < ED) ? f2bf(W[r * ED + j]) : (unsigned short)0;
        float whv = Whh[r * HD + tid];
        for (int j = tid; j < HD; j += 256) {
            Uh[r * HD + j] = (_Float16)U[r * HD + j];
            Wihh[r * HD + j] = (_Float16)Wih[r * HD + j];
            Whhh[r * HD + j] = (_Float16)Whh[r * HD + j];
        }
        if (r < 512) {
            float v = fabsf(whv);
            for (int o = 32; o; o >>= 1) v = fmaxf(v, __shfl_xor(v, o));
            if ((tid & 63) == 0) smax[tid >> 6] = v;
            __syncthreads();
            float am = fmaxf(fmaxf(smax[0], smax[1]), fmaxf(smax[2], smax[3]));
            float inv = (am > 0.f) ? 127.f / am : 0.f;
            int qi = (int)rintf(whv * inv);
            qi = max(-127, min(127, qi));
            Wq[r * HD + tid] = (signed char)qi;
            if (tid == 0) rowscale[r] = (am / 127.f) * (SH / 127.f);
        }
    } else if (bid < 798) {
        int idx = bid - 768;
        int d = idx / 3, part = idx - d * 3;
        int n = part * 256 + tid;
        float s = 0.f;
        for (int h = 0; h < HD; ++h) s += Dm[n * HD + h] * q[d * HD + h];
        Dq[d * TH + n] = s;
    } else {
        if (tid < HD) {
            float s = 0.f;
            for (int k = 0; k < 100; ++k) s += mlpW[tid * 100 + k] * DT[k];
            tv[tid] = tanh_(s + mlpb[tid]);
        }
        // combined bias for gi: bih + bhh for r/z rows (bhh_n must stay inside r*(.))
        for (int r = tid; r < TH; r += 256)
            bias2[r] = bih[r] + ((r < 512) ? bhh[r] : 0.f);
    }
}

// ---------------- phase B: pre[m][n] = (x @ W^T)[m][n] + Dq_table[dep(m)][n] + b[n] ----------------
__launch_bounds__(256, 2)
__global__ void k_phaseB(const int* __restrict__ sIdx, const int* __restrict__ depT,
                         const float* __restrict__ emb, const unsigned short* __restrict__ Wb,
                         const float* __restrict__ Dq, const float* __restrict__ bias,
                         unsigned short* __restrict__ pre) {
    __shared__ float dq_s[10 * 772];
    __shared__ float b_s[TH];
    __shared__ int dep_s[32];
    __shared__ int idx_s[32];
    int tid = threadIdx.x;
    int c0 = blockIdx.x * 32;
    for (int i = tid; i < 10 * 768; i += 256) {
        int d = i / 768, n = i - d * 768;
        dq_s[d * 772 + n] = Dq[i];
    }
    for (int i = tid; i < TH; i += 256) b_s[i] = bias[i];
    if (tid < 32) {
        int m = c0 + tid;
        idx_s[tid] = sIdx[m];
        int l = m & 63, s = m >> 6;
        dep_s[tid] = (l == 63) ? 9 : depT[s * 63 + l];
    }
    __syncthreads();

    int lane = tid & 63;
    int w = tid >> 6;
    int quad = lane >> 4, l16 = lane & 15;

    const float* xr0 = emb + (long)idx_s[l16] * ED;
    const float* xr1 = emb + (long)idx_s[16 + l16] * ED;

    f4 acc[2][12];
#pragma unroll
    for (int cs = 0; cs < 2; ++cs)
#pragma unroll
        for (int ms = 0; ms < 12; ++ms) acc[cs][ms] = (f4){0.f, 0.f, 0.f, 0.f};

    const unsigned short* wbase = Wb + (w * 192 + l16) * EP;

#pragma unroll
    for (int kt = 0; kt < 10; ++kt) {
        int k0 = kt * 32 + quad * 8;
        short8 bf[2];
#pragma unroll
        for (int cs = 0; cs < 2; ++cs) {
            const float* xr = cs ? xr1 : xr0;
            float xv[8];
            if (k0 + 8 <= ED) {
                float4 f0 = *(const float4*)(xr + k0);
                float4 f1 = *(const float4*)(xr + k0 + 4);
                xv[0] = f0.x; xv[1] = f0.y; xv[2] = f0.z; xv[3] = f0.w;
                xv[4] = f1.x; xv[5] = f1.y; xv[6] = f1.z; xv[7] = f1.w;
            } else {
#pragma unroll
                for (int j = 0; j < 8; ++j) xv[j] = (k0 + j < ED) ? xr[k0 + j] : 0.f;
            }
            short8 t;
#pragma unroll
            for (int j = 0; j < 8; ++j) t[j] = (short)f2bf(xv[j]);
            bf[cs] = t;
        }
#pragma unroll
        for (int ms = 0; ms < 12; ++ms) {
            short8 af = *(const short8*)(wbase + ms * 16 * EP + k0);
            acc[0][ms] = __builtin_amdgcn_mfma_f32_16x16x32_bf16(af, bf[0], acc[0][ms], 0, 0, 0);
            acc[1][ms] = __builtin_amdgcn_mfma_f32_16x16x32_bf16(af, bf[1], acc[1][ms], 0, 0, 0);
        }
    }

#pragma unroll
    for (int cs = 0; cs < 2; ++cs) {
        int xr = c0 + cs * 16 + l16;
        int dep = dep_s[cs * 16 + l16];
        unsigned short* prow = pre + (long)xr * TH;
#pragma unroll
        for (int ms = 0; ms < 12; ++ms) {
            int ncol = w * 192 + ms * 16 + quad * 4;
            f4 dq4 = *(const f4*)&dq_s[dep * 772 + ncol];
            f4 b4 = *(const f4*)&b_s[ncol];
            unsigned int lo = (unsigned int)f2bf(acc[cs][ms][0] + dq4[0] + b4[0]) |
                              ((unsigned int)f2bf(acc[cs][ms][1] + dq4[1] + b4[1]) << 16);
            unsigned int hi = (unsigned int)f2bf(acc[cs][ms][2] + dq4[2] + b4[2]) |
                              ((unsigned int)f2bf(acc[cs][ms][3] + dq4[3] + b4[3]) << 16);
            uint2 v; v.x = lo; v.y = hi;
            *(uint2*)(prow + ncol) = v;
        }
    }
}

// ---------------- phase C: U AGPR-resident MFMA, 16 sentences/WG, pre-loads hoisted ----------------
// epilogue writes gi = Wih@sv + bias2  (bias2 = bih + bhh folded for r/z rows)
__global__ void __launch_bounds__(768) k_phaseC(
                         const unsigned short* __restrict__ pre,
                         const _Float16* __restrict__ Uh,
                         const _Float16* __restrict__ Wihh,
                         const float* __restrict__ bias2,
                         float* __restrict__ gi) {
    __shared__ __align__(16) uint4 hfr[512];
    __shared__ __align__(16) float tot[16 * 772];
    int tid = threadIdx.x;
    int lane = tid & 63, w = tid >> 6, quad = lane >> 4, l16 = lane & 15;
    int s0 = blockIdx.x * 16;

    uint4 frag[32];
    {
        const _Float16* base = Uh + (w * 64 + l16) * HD;
#pragma unroll
        for (int t = 0; t < 4; ++t)
#pragma unroll
            for (int kt = 0; kt < 8; ++kt)
                frag[t * 8 + kt] = *(const uint4*)(base + t * 16 * HD + kt * 32 + quad * 8);
    }

    int us = tid >> 5;
    int jg = tid & 31;
    int j0 = jg * 8;
    int hcell = (j0 >> 5) * 64 + 16 * ((j0 >> 3) & 3) + us;
    uint4 hcp;

    if (tid < 512) {
        const unsigned short* prow = pre + ((long)(s0 + us) * LW + 63) * TH;
        float iv[8], uv[8], hcv[8];
        load8bf(prow + 256 + j0, iv);
        load8bf(prow + 512 + j0, uv);
#pragma unroll
        for (int r = 0; r < 8; ++r) hcv[r] = tanh_(sigm(iv[r]) * tanh_(uv[r]));
        hcp.x = pack_h2(hcv[0], hcv[1]); hcp.y = pack_h2(hcv[2], hcv[3]);
        hcp.z = pack_h2(hcv[4], hcv[5]); hcp.w = pack_h2(hcv[6], hcv[7]);
        hfr[hcell] = hcp;
    }
    __syncthreads();

    int mb = w * 64 + quad * 4;

    for (int step = 0; step < 63; ++step) {
        int l = 62 - step;
        uint2 praw[6];
        if (tid < 512) {
            const unsigned short* prow = pre + ((long)(s0 + us) * LW + l) * TH;
#pragma unroll
            for (int g = 0; g < 3; ++g) {
                praw[2 * g]     = *(const uint2*)(prow + g * 256 + j0);
                praw[2 * g + 1] = *(const uint2*)(prow + g * 256 + j0 + 4);
            }
        }
        f4 a0 = (f4){0,0,0,0}, a1 = (f4){0,0,0,0}, a2 = (f4){0,0,0,0}, a3 = (f4){0,0,0,0};
#pragma unroll
        for (int kt = 0; kt < 8; ++kt) {
            half8 b = __builtin_bit_cast(half8, hfr[kt * 64 + lane]);
            a0 = __builtin_amdgcn_mfma_f32_16x16x32_f16(__builtin_bit_cast(half8, frag[kt]), b, a0, 0, 0, 0);
            a1 = __builtin_amdgcn_mfma_f32_16x16x32_f16(__builtin_bit_cast(half8, frag[8 + kt]), b, a1, 0, 0, 0);
            a2 = __builtin_amdgcn_mfma_f32_16x16x32_f16(__builtin_bit_cast(half8, frag[16 + kt]), b, a2, 0, 0, 0);
            a3 = __builtin_amdgcn_mfma_f32_16x16x32_f16(__builtin_bit_cast(half8, frag[24 + kt]), b, a3, 0, 0, 0);
        }
        float* tr = tot + l16 * 772;
        *(f4*)&tr[mb] = a0;
        *(f4*)&tr[mb + 16] = a1;
        *(f4*)&tr[mb + 32] = a2;
        *(f4*)&tr[mb + 48] = a3;
        __syncthreads();
        if (tid < 512) {
            const float* ts = tot + us * 772;
            float hcv[8];
            h2 px = __builtin_bit_cast(h2, hcp.x); h2 py = __builtin_bit_cast(h2, hcp.y);
            h2 pz = __builtin_bit_cast(h2, hcp.z); h2 pw = __builtin_bit_cast(h2, hcp.w);
            hcv[0] = (float)px.x; hcv[1] = (float)px.y; hcv[2] = (float)py.x; hcv[3] = (float)py.y;
            hcv[4] = (float)pz.x; hcv[5] = (float)pz.y; hcv[6] = (float)pw.x; hcv[7] = (float)pw.y;
#pragma unroll
            for (int hf = 0; hf < 2; ++hf) {
                int jb = j0 + hf * 4;
                float pf[4], pi_[4], pu[4];
                ubf4(praw[hf], pf);
                ubf4(praw[2 + hf], pi_);
                ubf4(praw[4 + hf], pu);
                f4 tf = *(const f4*)&ts[jb];
                f4 ti = *(const f4*)&ts[256 + jb];
                f4 tu = *(const f4*)&ts[512 + jb];
#pragma unroll
                for (int r = 0; r < 4; ++r) {
                    float ff = tf[r] + pf[r];
                    float ii = ti[r] + pi_[r];
                    float uu = tu[r] + pu[r];
                    hcv[hf * 4 + r] = tanh_(sigm(ii) * tanh_(uu) + sigm(ff) * hcv[hf * 4 + r]);
                }
            }
            hcp.x = pack_h2(hcv[0], hcv[1]); hcp.y = pack_h2(hcv[2], hcv[3]);
            hcp.z = pack_h2(hcv[4], hcv[5]); hcp.w = pack_h2(hcv[6], hcv[7]);
            hfr[hcell] = hcp;
        }
        __syncthreads();
    }

    {
        const _Float16* base = Wihh + (w * 64 + l16) * HD;
#pragma unroll
        for (int t = 0; t < 4; ++t)
#pragma unroll
            for (int kt = 0; kt < 8; ++kt)
                frag[t * 8 + kt] = *(const uint4*)(base + t * 16 * HD + kt * 32 + quad * 8);
    }
    f4 a0 = (f4){0,0,0,0}, a1 = (f4){0,0,0,0}, a2 = (f4){0,0,0,0}, a3 = (f4){0,0,0,0};
#pragma unroll
    for (int kt = 0; kt < 8; ++kt) {
        half8 b = __builtin_bit_cast(half8, hfr[kt * 64 + lane]);
        a0 = __builtin_amdgcn_mfma_f32_16x16x32_f16(__builtin_bit_cast(half8, frag[kt]), b, a0, 0, 0, 0);
        a1 = __builtin_amdgcn_mfma_f32_16x16x32_f16(__builtin_bit_cast(half8, frag[8 + kt]), b, a1, 0, 0, 0);
        a2 = __builtin_amdgcn_mfma_f32_16x16x32_f16(__builtin_bit_cast(half8, frag[16 + kt]), b, a2, 0, 0, 0);
        a3 = __builtin_amdgcn_mfma_f32_16x16x32_f16(__builtin_bit_cast(half8, frag[24 + kt]), b, a3, 0, 0, 0);
    }
    float* go = gi + (long)(s0 + l16) * TH;
    f4 b0 = *(const f4*)(bias2 + mb);
    f4 b1 = *(const f4*)(bias2 + mb + 16);
    f4 b2 = *(const f4*)(bias2 + mb + 32);
    f4 b3 = *(const f4*)(bias2 + mb + 48);
    *(f4*)(go + mb) = a0 + b0;
    *(f4*)(go + mb + 16) = a1 + b1;
    *(f4*)(go + mb + 32) = a2 + b2;
    *(f4*)(go + mb + 48) = a3 + b3;
}

// ---------------- GRU v7: aligned row ownership, in-register update, 1 barrier/step ----------------
// Wave w owns r rows [w*32,w*32+32), z rows 256+[w*32,..), n rows 512+[w*32,..).
// B columns are identical (matvec) => every lane holds full D values => gate update is
// done in-register in all lanes; only l16==0 lanes write h to the ping-pong LDS buffer.
__global__ void __launch_bounds__(512) k_gru(
                      const signed char* __restrict__ Wq, const float* __restrict__ rowscale,
                      const _Float16* __restrict__ Whhh, const float* __restrict__ bhh,
                      const float* __restrict__ gi, const float* __restrict__ h0,
                      const float* __restrict__ tv,
                      const float* __restrict__ gateW, const float* __restrict__ gateU,
                      const float* __restrict__ gateb,
                      const float* __restrict__ outW, const float* __restrict__ outb,
                      float* __restrict__ out) {
    __shared__ __align__(16) _Float16 hbuf[2][HD];   // ping-pong h (f16)
    __shared__ __align__(16) signed char qbuf[2][HD];// ping-pong h (i8, scale SH/127)
    __shared__ float hts[HD];
    __shared__ float sgs[512];
    __shared__ float vvs[HD];
    __shared__ float lg[8];

    int tid = threadIdx.x;
    int lane = tid & 63, w = tid >> 6, quad = lane >> 4, l16 = lane & 15;
    int j0 = w * 32 + quad * 4;     // first h index this lane handles (tile c=0)

    // i8 fragments: r tiles rows w*32+c*16, z tiles rows 256+w*32+c*16
    i4 far_[2][4], faz[2][4];
#pragma unroll
    for (int c = 0; c < 2; ++c) {
        const signed char* qr_ = Wq + (long)(w * 32 + c * 16 + l16) * HD;
        const signed char* qz_ = Wq + (long)(256 + w * 32 + c * 16 + l16) * HD;
#pragma unroll
        for (int kc = 0; kc < 4; ++kc) {
            far_[c][kc] = *(const i4*)(qr_ + kc * 64 + quad * 16);
            faz[c][kc] = *(const i4*)(qz_ + kc * 64 + quad * 16);
        }
    }
    // f16 fragments: n tiles rows 512+w*32+c*16
    uint4 fn[2][8];
#pragma unroll
    for (int c = 0; c < 2; ++c) {
        const _Float16* nb = Whhh + (long)(512 + w * 32 + c * 16 + l16) * HD;
#pragma unroll
        for (int kc = 0; kc < 8; ++kc)
            fn[c][kc] = *(const uint4*)(nb + kc * 32 + quad * 8);
    }
    // per-row constants
    f4 rsr[2], rsz[2], bn[2];
#pragma unroll
    for (int c = 0; c < 2; ++c) {
        rsr[c] = *(const f4*)(rowscale + j0 + c * 16);
        rsz[c] = *(const f4*)(rowscale + 256 + j0 + c * 16);
        bn[c] = *(const f4*)(bhh + 512 + j0 + c * 16);
    }

    // init h
    f4 hv[2];
#pragma unroll
    for (int c = 0; c < 2; ++c) hv[c] = *(const f4*)(h0 + j0 + c * 16);
    if (l16 == 0) {
#pragma unroll
        for (int c = 0; c < 2; ++c) {
            int j = j0 + c * 16;
            uint2 hp; hp.x = pack_h2(hv[c][0], hv[c][1]); hp.y = pack_h2(hv[c][2], hv[c][3]);
            *(uint2*)&hbuf[0][j] = hp;
            int qq = 0;
#pragma unroll
            for (int r = 0; r < 4; ++r) {
                float hc = fminf(fmaxf(hv[c][r], -SH), SH);
                int qi = (int)rintf(hc * (127.f / SH));
                qq |= (qi & 0xff) << (8 * r);
            }
            *(int*)&qbuf[0][j] = qq;
        }
    }
    __syncthreads();

    for (int t = 0; t < NS; ++t) {
        int p = t & 1;
        // prefetch gi (addresses depend on quad only; all lanes load, HW dedups)
        const float* g = gi + (long)t * TH;
        f4 gr[2], gz[2], gn[2];
#pragma unroll
        for (int c = 0; c < 2; ++c) {
            gr[c] = *(const f4*)(g + j0 + c * 16);
            gz[c] = *(const f4*)(g + 256 + j0 + c * 16);
            gn[c] = *(const f4*)(g + 512 + j0 + c * 16);
        }
        // matvec
        i4 qr[2], qz[2];
        f4 an[2];
#pragma unroll
        for (int c = 0; c < 2; ++c) { qr[c] = (i4){0,0,0,0}; qz[c] = (i4){0,0,0,0}; an[c] = (f4){0,0,0,0}; }
#pragma unroll
        for (int kc = 0; kc < 4; ++kc) {
            i4 b = *(const i4*)&qbuf[p][kc * 64 + quad * 16];
            qr[0] = __builtin_amdgcn_mfma_i32_16x16x64_i8(far_[0][kc], b, qr[0], 0, 0, 0);
            qr[1] = __builtin_amdgcn_mfma_i32_16x16x64_i8(far_[1][kc], b, qr[1], 0, 0, 0);
            qz[0] = __builtin_amdgcn_mfma_i32_16x16x64_i8(faz[0][kc], b, qz[0], 0, 0, 0);
            qz[1] = __builtin_amdgcn_mfma_i32_16x16x64_i8(faz[1][kc], b, qz[1], 0, 0, 0);
        }
#pragma unroll
        for (int kc = 0; kc < 8; ++kc) {
            half8 b = __builtin_bit_cast(half8, *(const uint4*)&hbuf[p][kc * 32 + quad * 8]);
            an[0] = __builtin_amdgcn_mfma_f32_16x16x32_f16(__builtin_bit_cast(half8, fn[0][kc]), b, an[0], 0, 0, 0);
            an[1] = __builtin_amdgcn_mfma_f32_16x16x32_f16(__builtin_bit_cast(half8, fn[1][kc]), b, an[1], 0, 0, 0);
        }
        // in-register gate update (all lanes hold identical D values)
#pragma unroll
        for (int c = 0; c < 2; ++c) {
#pragma unroll
            for (int r = 0; r < 4; ++r) {
                float rv = sigm(gr[c][r] + (float)qr[c][r] * rsr[c][r]);
                float zv = sigm(gz[c][r] + (float)qz[c][r] * rsz[c][r]);
                float nv = tanh_(gn[c][r] + rv * (an[c][r] + bn[c][r]));
                hv[c][r] = (1.f - zv) * nv + zv * hv[c][r];
            }
        }
        if (l16 == 0) {
#pragma unroll
            for (int c = 0; c < 2; ++c) {
                int j = j0 + c * 16;
                uint2 hp; hp.x = pack_h2(hv[c][0], hv[c][1]); hp.y = pack_h2(hv[c][2], hv[c][3]);
                *(uint2*)&hbuf[p ^ 1][j] = hp;
                int qq = 0;
#pragma unroll
                for (int r = 0; r < 4; ++r) {
                    float hc = fminf(fmaxf(hv[c][r], -SH), SH);
                    int qi = (int)rintf(hc * (127.f / SH));
                    qq |= (qi & 0xff) << (8 * r);
                }
                *(int*)&qbuf[p ^ 1][j] = qq;
            }
        }
        __syncthreads();
    }

    // head
    if (l16 == 0) {
        *(f4*)&hts[j0] = hv[0];
        *(f4*)&hts[j0 + 16] = hv[1];
    }
    __syncthreads();
    {
        float s = gateb[tid];
        for (int k = 0; k < HD; ++k)
            s += gateW[tid * HD + k] * hts[k] + gateU[tid * HD + k] * tv[k];
        sgs[tid] = sigm(s);
    }
    __syncthreads();
    if (tid < HD) vvs[tid] = tanh_(sgs[tid] * hts[tid] + sgs[256 + tid] * tv[tid]);
    __syncthreads();
    if (tid < 5) {
        float s = outb[tid];
        for (int k = 0; k < HD; ++k) s += outW[tid * HD + k] * vvs[k];
        lg[tid] = s;
    }
    __syncthreads();
    if (tid == 0) {
        float m = lg[0];
        for (int i = 1; i < 5; ++i) m = fmaxf(m, lg[i]);
        float e[5], sum = 0.f;
        for (int i = 0; i < 5; ++i) { e[i] = __expf(lg[i] - m); sum += e[i]; }
        for (int i = 0; i < 5; ++i) out[i] = e[i] / sum;
    }
}

extern "C" void kernel_launch(void* const* d_in, const int* in_sizes, int n_in,
                              void* d_out, int out_size, void* d_ws, size_t ws_size,
                              hipStream_t stream) {
    (void)in_sizes; (void)n_in; (void)out_size; (void)ws_size;
    const int* sIdx = (const int*)d_in[0];
    const int* depT = (const int*)d_in[1];
    const float* DT = (const float*)d_in[2];
    const float* h0 = (const float*)d_in[3];
    const float* emb = (const float*)d_in[4];
    const float* q = (const float*)d_in[5];
    const float* W = (const float*)d_in[6];
    const float* U = (const float*)d_in[7];
    const float* Dm = (const float*)d_in[8];
    const float* b = (const float*)d_in[9];
    const float* Wih = (const float*)d_in[10];
    const float* Whh = (const float*)d_in[11];
    const float* bih = (const float*)d_in[12];
    const float* bhh = (const float*)d_in[13];
    const float* gateW = (const float*)d_in[14];
    const float* gateU = (const float*)d_in[15];
    const float* gateb = (const float*)d_in[16];
    const float* mlpW = (const float*)d_in[17];
    const float* mlpb = (const float*)d_in[18];
    const float* outW = (const float*)d_in[19];
    const float* outb = (const float*)d_in[20];

    char* ws = (char*)d_ws;
    unsigned short* Wb = (unsigned short*)ws;   ws += 768 * 320 * 2;
    _Float16* Uh = (_Float16*)ws;               ws += 768 * 256 * 2;
    _Float16* Wihh = (_Float16*)ws;             ws += 768 * 256 * 2;
    _Float16* Whhh = (_Float16*)ws;             ws += 768 * 256 * 2;
    signed char* Wq = (signed char*)ws;         ws += 512 * 256;
    float* rowscale = (float*)ws;               ws += 512 * 4;
    float* bias2 = (float*)ws;                  ws += 768 * 4;
    float* Dq = (float*)ws;                     ws += 10 * 768 * 4;
    float* tv = (float*)ws;                     ws += 1024;
    ws = (char*)d_ws + ((((size_t)(ws - (char*)d_ws)) + 4095) & ~(size_t)4095);
    unsigned short* pre = (unsigned short*)ws;  ws += (size_t)65536 * 768 * 2;
    float* gi = (float*)ws;                     ws += (size_t)1024 * 768 * 4;

    k_prep<<<dim3(799), dim3(256), 0, stream>>>(W, U, Wih, Whh, q, Dm, DT, mlpW, mlpb,
                                                bih, bhh,
                                                Wb, Uh, Wihh, Whhh, Wq, rowscale, bias2, Dq, tv);
    k_phaseB<<<dim3(2048), dim3(256), 0, stream>>>(sIdx, depT, emb, Wb, Dq, b, pre);
    k_phaseC<<<dim3(64), dim3(768), 0, stream>>>(pre, Uh, Wihh, bias2, gi);
    k_gru<<<dim3(1), dim3(512), 0, stream>>>(Wq, rowscale, Whhh, bhh, gi, h0, tv,
                                             gateW, gateU, gateb, outW, outb, (float*)d_out);
}

// Round 8
// 1443.550 us; speedup vs baseline: 1.4786x; 1.4786x over previous
//
#include <hip/hip_runtime.h>

typedef short short8 __attribute__((ext_vector_type(8)));
typedef float f4 __attribute__((ext_vector_type(4)));
typedef int i4 __attribute__((ext_vector_type(4)));
typedef _Float16 half8 __attribute__((ext_vector_type(8)));
typedef _Float16 h2 __attribute__((ext_vector_type(2)));

#define HD 256
#define ED 300
#define EP 320
#define TH 768
#define NS 1024
#define LW 64
#define SH 4.5f

__device__ __forceinline__ unsigned short f2bf(float f) {
    unsigned int u = __float_as_uint(f);
    u = (u + 0x7FFFu + ((u >> 16) & 1u)) >> 16;
    return (unsigned short)u;
}
__device__ __forceinline__ float bf2f(unsigned short s) {
    return __uint_as_float(((unsigned int)s) << 16);
}
__device__ __forceinline__ float sigm(float x) {
    return __builtin_amdgcn_rcpf(1.f + __expf(-x));
}
__device__ __forceinline__ float tanh_(float x) {
    x = fminf(fmaxf(x, -15.f), 15.f);
    return 1.f - 2.f * __builtin_amdgcn_rcpf(1.f + __expf(2.f * x));
}
__device__ __forceinline__ unsigned int pack_h2(float a, float b) {
    h2 p; p.x = (_Float16)a; p.y = (_Float16)b;
    return __builtin_bit_cast(unsigned int, p);
}

__device__ __forceinline__ void load8bf(const unsigned short* p, float* o) {
    uint4 a = *(const uint4*)p;
    o[0] = bf2f((unsigned short)(a.x & 0xffff)); o[1] = bf2f((unsigned short)(a.x >> 16));
    o[2] = bf2f((unsigned short)(a.y & 0xffff)); o[3] = bf2f((unsigned short)(a.y >> 16));
    o[4] = bf2f((unsigned short)(a.z & 0xffff)); o[5] = bf2f((unsigned short)(a.z >> 16));
    o[6] = bf2f((unsigned short)(a.w & 0xffff)); o[7] = bf2f((unsigned short)(a.w >> 16));
}
__device__ __forceinline__ void ubf4(uint2 a, float* o) {
    o[0] = bf2f((unsigned short)(a.x & 0xffff)); o[1] = bf2f((unsigned short)(a.x >> 16));
    o[2] = bf2f((unsigned short)(a.y & 0xffff)); o[3] = bf2f((unsigned short)(a.y >> 16));
}

// ---------------- prep: weight conversions, i8 quantization, Dq table, topic vector ----------------
__global__ void k_prep(const float* __restrict__ W, const float* __restrict__ U,
                       const float* __restrict__ Wih, const float* __restrict__ Whh,
                       const float* __restrict__ q, const float* __restrict__ Dm,
                       const float* __restrict__ DT, const float* __restrict__ mlpW,
                       const float* __restrict__ mlpb,
                       const float* __restrict__ bih, const float* __restrict__ bhh,
                       unsigned short* __restrict__ Wb, _Float16* __restrict__ Uh,
                       _Float16* __restrict__ Wihh, _Float16* __restrict__ Whhh,
                       signed char* __restrict__ Wq, float* __restrict__ rowscale,
                       float* __restrict__ bias2,
                       float* __restrict__ Dq, float* __restrict__ tv) {
    __shared__ float smax[4];
    int bid = blockIdx.x, tid = threadIdx.x;
    if (bid < 768) {
        int r = bid;
        for (int j = tid; j < EP; j += 256)
            Wb[r * EP + j] = (j < ED) ? f2bf(W[r * ED + j]) : (unsigned short)0;
        float whv = Whh[r * HD + tid];
        for (int j = tid; j < HD; j += 256) {
            Uh[r * HD + j] = (_Float16)U[r * HD + j];
            Wihh[r * HD + j] = (_Float16)Wih[r * HD + j];
            Whhh[r * HD + j] = (_Float16)Whh[r * HD + j];
        }
        if (r < 512) {
            float v = fabsf(whv);
            for (int o = 32; o; o >>= 1) v = fmaxf(v, __shfl_xor(v, o));
            if ((tid & 63) == 0) smax[tid >> 6] = v;
            __syncthreads();
            float am = fmaxf(fmaxf(smax[0], smax[1]), fmaxf(smax[2], smax[3]));
            float inv = (am > 0.f) ? 127.f / am : 0.f;
            int qi = (int)rintf(whv * inv);
            qi = max(-127, min(127, qi));
            Wq[r * HD + tid] = (signed char)qi;
            if (tid == 0) rowscale[r] = (am / 127.f) * (SH / 127.f);
        }
    } else if (bid < 798) {
        int idx = bid - 768;
        int d = idx / 3, part = idx - d * 3;
        int n = part * 256 + tid;
        float s = 0.f;
        for (int h = 0; h < HD; ++h) s += Dm[n * HD + h] * q[d * HD + h];
        Dq[d * TH + n] = s;
    } else {
        if (tid < HD) {
            float s = 0.f;
            for (int k = 0; k < 100; ++k) s += mlpW[tid * 100 + k] * DT[k];
            tv[tid] = tanh_(s + mlpb[tid]);
        }
        for (int r = tid; r < TH; r += 256)
            bias2[r] = bih[r] + ((r < 512) ? bhh[r] : 0.f);
    }
}

// ---------------- phase B: pre[m][n] = (x @ W^T)[m][n] + Dq_table[dep(m)][n] + b[n] ----------------
__launch_bounds__(256, 2)
__global__ void k_phaseB(const int* __restrict__ sIdx, const int* __restrict__ depT,
                         const float* __restrict__ emb, const unsigned short* __restrict__ Wb,
                         const float* __restrict__ Dq, const float* __restrict__ bias,
                         unsigned short* __restrict__ pre) {
    __shared__ float dq_s[10 * 772];
    __shared__ float b_s[TH];
    __shared__ int dep_s[32];
    __shared__ int idx_s[32];
    int tid = threadIdx.x;
    int c0 = blockIdx.x * 32;
    for (int i = tid; i < 10 * 768; i += 256) {
        int d = i / 768, n = i - d * 768;
        dq_s[d * 772 + n] = Dq[i];
    }
    for (int i = tid; i < TH; i += 256) b_s[i] = bias[i];
    if (tid < 32) {
        int m = c0 + tid;
        idx_s[tid] = sIdx[m];
        int l = m & 63, s = m >> 6;
        dep_s[tid] = (l == 63) ? 9 : depT[s * 63 + l];
    }
    __syncthreads();

    int lane = tid & 63;
    int w = tid >> 6;
    int quad = lane >> 4, l16 = lane & 15;

    const float* xr0 = emb + (long)idx_s[l16] * ED;
    const float* xr1 = emb + (long)idx_s[16 + l16] * ED;

    f4 acc[2][12];
#pragma unroll
    for (int cs = 0; cs < 2; ++cs)
#pragma unroll
        for (int ms = 0; ms < 12; ++ms) acc[cs][ms] = (f4){0.f, 0.f, 0.f, 0.f};

    const unsigned short* wbase = Wb + (w * 192 + l16) * EP;

#pragma unroll
    for (int kt = 0; kt < 10; ++kt) {
        int k0 = kt * 32 + quad * 8;
        short8 bf[2];
#pragma unroll
        for (int cs = 0; cs < 2; ++cs) {
            const float* xr = cs ? xr1 : xr0;
            float xv[8];
            if (k0 + 8 <= ED) {
                float4 f0 = *(const float4*)(xr + k0);
                float4 f1 = *(const float4*)(xr + k0 + 4);
                xv[0] = f0.x; xv[1] = f0.y; xv[2] = f0.z; xv[3] = f0.w;
                xv[4] = f1.x; xv[5] = f1.y; xv[6] = f1.z; xv[7] = f1.w;
            } else {
#pragma unroll
                for (int j = 0; j < 8; ++j) xv[j] = (k0 + j < ED) ? xr[k0 + j] : 0.f;
            }
            short8 t;
#pragma unroll
            for (int j = 0; j < 8; ++j) t[j] = (short)f2bf(xv[j]);
            bf[cs] = t;
        }
#pragma unroll
        for (int ms = 0; ms < 12; ++ms) {
            short8 af = *(const short8*)(wbase + ms * 16 * EP + k0);
            acc[0][ms] = __builtin_amdgcn_mfma_f32_16x16x32_bf16(af, bf[0], acc[0][ms], 0, 0, 0);
            acc[1][ms] = __builtin_amdgcn_mfma_f32_16x16x32_bf16(af, bf[1], acc[1][ms], 0, 0, 0);
        }
    }

#pragma unroll
    for (int cs = 0; cs < 2; ++cs) {
        int xr = c0 + cs * 16 + l16;
        int dep = dep_s[cs * 16 + l16];
        unsigned short* prow = pre + (long)xr * TH;
#pragma unroll
        for (int ms = 0; ms < 12; ++ms) {
            int ncol = w * 192 + ms * 16 + quad * 4;
            f4 dq4 = *(const f4*)&dq_s[dep * 772 + ncol];
            f4 b4 = *(const f4*)&b_s[ncol];
            unsigned int lo = (unsigned int)f2bf(acc[cs][ms][0] + dq4[0] + b4[0]) |
                              ((unsigned int)f2bf(acc[cs][ms][1] + dq4[1] + b4[1]) << 16);
            unsigned int hi = (unsigned int)f2bf(acc[cs][ms][2] + dq4[2] + b4[2]) |
                              ((unsigned int)f2bf(acc[cs][ms][3] + dq4[3] + b4[3]) << 16);
            uint2 v; v.x = lo; v.y = hi;
            *(uint2*)(prow + ncol) = v;
        }
    }
}

// ---------------- phase C: U AGPR-resident MFMA, 16 sentences/WG, pre-loads hoisted ----------------
__global__ void __launch_bounds__(768) k_phaseC(
                         const unsigned short* __restrict__ pre,
                         const _Float16* __restrict__ Uh,
                         const _Float16* __restrict__ Wihh,
                         const float* __restrict__ bias2,
                         float* __restrict__ gi) {
    __shared__ __align__(16) uint4 hfr[512];
    __shared__ __align__(16) float tot[16 * 772];
    int tid = threadIdx.x;
    int lane = tid & 63, w = tid >> 6, quad = lane >> 4, l16 = lane & 15;
    int s0 = blockIdx.x * 16;

    uint4 frag[32];
    {
        const _Float16* base = Uh + (w * 64 + l16) * HD;
#pragma unroll
        for (int t = 0; t < 4; ++t)
#pragma unroll
            for (int kt = 0; kt < 8; ++kt)
                frag[t * 8 + kt] = *(const uint4*)(base + t * 16 * HD + kt * 32 + quad * 8);
    }

    int us = tid >> 5;
    int jg = tid & 31;
    int j0 = jg * 8;
    int hcell = (j0 >> 5) * 64 + 16 * ((j0 >> 3) & 3) + us;
    uint4 hcp;

    if (tid < 512) {
        const unsigned short* prow = pre + ((long)(s0 + us) * LW + 63) * TH;
        float iv[8], uv[8], hcv[8];
        load8bf(prow + 256 + j0, iv);
        load8bf(prow + 512 + j0, uv);
#pragma unroll
        for (int r = 0; r < 8; ++r) hcv[r] = tanh_(sigm(iv[r]) * tanh_(uv[r]));
        hcp.x = pack_h2(hcv[0], hcv[1]); hcp.y = pack_h2(hcv[2], hcv[3]);
        hcp.z = pack_h2(hcv[4], hcv[5]); hcp.w = pack_h2(hcv[6], hcv[7]);
        hfr[hcell] = hcp;
    }
    __syncthreads();

    int mb = w * 64 + quad * 4;

    for (int step = 0; step < 63; ++step) {
        int l = 62 - step;
        uint2 praw[6];
        if (tid < 512) {
            const unsigned short* prow = pre + ((long)(s0 + us) * LW + l) * TH;
#pragma unroll
            for (int g = 0; g < 3; ++g) {
                praw[2 * g]     = *(const uint2*)(prow + g * 256 + j0);
                praw[2 * g + 1] = *(const uint2*)(prow + g * 256 + j0 + 4);
            }
        }
        f4 a0 = (f4){0,0,0,0}, a1 = (f4){0,0,0,0}, a2 = (f4){0,0,0,0}, a3 = (f4){0,0,0,0};
#pragma unroll
        for (int kt = 0; kt < 8; ++kt) {
            half8 b = __builtin_bit_cast(half8, hfr[kt * 64 + lane]);
            a0 = __builtin_amdgcn_mfma_f32_16x16x32_f16(__builtin_bit_cast(half8, frag[kt]), b, a0, 0, 0, 0);
            a1 = __builtin_amdgcn_mfma_f32_16x16x32_f16(__builtin_bit_cast(half8, frag[8 + kt]), b, a1, 0, 0, 0);
            a2 = __builtin_amdgcn_mfma_f32_16x16x32_f16(__builtin_bit_cast(half8, frag[16 + kt]), b, a2, 0, 0, 0);
            a3 = __builtin_amdgcn_mfma_f32_16x16x32_f16(__builtin_bit_cast(half8, frag[24 + kt]), b, a3, 0, 0, 0);
        }
        float* tr = tot + l16 * 772;
        *(f4*)&tr[mb] = a0;
        *(f4*)&tr[mb + 16] = a1;
        *(f4*)&tr[mb + 32] = a2;
        *(f4*)&tr[mb + 48] = a3;
        __syncthreads();
        if (tid < 512) {
            const float* ts = tot + us * 772;
            float hcv[8];
            h2 px = __builtin_bit_cast(h2, hcp.x); h2 py = __builtin_bit_cast(h2, hcp.y);
            h2 pz = __builtin_bit_cast(h2, hcp.z); h2 pw = __builtin_bit_cast(h2, hcp.w);
            hcv[0] = (float)px.x; hcv[1] = (float)px.y; hcv[2] = (float)py.x; hcv[3] = (float)py.y;
            hcv[4] = (float)pz.x; hcv[5] = (float)pz.y; hcv[6] = (float)pw.x; hcv[7] = (float)pw.y;
#pragma unroll
            for (int hf = 0; hf < 2; ++hf) {
                int jb = j0 + hf * 4;
                float pf[4], pi_[4], pu[4];
                ubf4(praw[hf], pf);
                ubf4(praw[2 + hf], pi_);
                ubf4(praw[4 + hf], pu);
                f4 tf = *(const f4*)&ts[jb];
                f4 ti = *(const f4*)&ts[256 + jb];
                f4 tu = *(const f4*)&ts[512 + jb];
#pragma unroll
                for (int r = 0; r < 4; ++r) {
                    float ff = tf[r] + pf[r];
                    float ii = ti[r] + pi_[r];
                    float uu = tu[r] + pu[r];
                    hcv[hf * 4 + r] = tanh_(sigm(ii) * tanh_(uu) + sigm(ff) * hcv[hf * 4 + r]);
                }
            }
            hcp.x = pack_h2(hcv[0], hcv[1]); hcp.y = pack_h2(hcv[2], hcv[3]);
            hcp.z = pack_h2(hcv[4], hcv[5]); hcp.w = pack_h2(hcv[6], hcv[7]);
            hfr[hcell] = hcp;
        }
        __syncthreads();
    }

    {
        const _Float16* base = Wihh + (w * 64 + l16) * HD;
#pragma unroll
        for (int t = 0; t < 4; ++t)
#pragma unroll
            for (int kt = 0; kt < 8; ++kt)
                frag[t * 8 + kt] = *(const uint4*)(base + t * 16 * HD + kt * 32 + quad * 8);
    }
    f4 a0 = (f4){0,0,0,0}, a1 = (f4){0,0,0,0}, a2 = (f4){0,0,0,0}, a3 = (f4){0,0,0,0};
#pragma unroll
    for (int kt = 0; kt < 8; ++kt) {
        half8 b = __builtin_bit_cast(half8, hfr[kt * 64 + lane]);
        a0 = __builtin_amdgcn_mfma_f32_16x16x32_f16(__builtin_bit_cast(half8, frag[kt]), b, a0, 0, 0, 0);
        a1 = __builtin_amdgcn_mfma_f32_16x16x32_f16(__builtin_bit_cast(half8, frag[8 + kt]), b, a1, 0, 0, 0);
        a2 = __builtin_amdgcn_mfma_f32_16x16x32_f16(__builtin_bit_cast(half8, frag[16 + kt]), b, a2, 0, 0, 0);
        a3 = __builtin_amdgcn_mfma_f32_16x16x32_f16(__builtin_bit_cast(half8, frag[24 + kt]), b, a3, 0, 0, 0);
    }
    float* go = gi + (long)(s0 + l16) * TH;
    f4 b0 = *(const f4*)(bias2 + mb);
    f4 b1 = *(const f4*)(bias2 + mb + 16);
    f4 b2 = *(const f4*)(bias2 + mb + 32);
    f4 b3 = *(const f4*)(bias2 + mb + 48);
    *(f4*)(go + mb) = a0 + b0;
    *(f4*)(go + mb + 16) = a1 + b1;
    *(f4*)(go + mb + 32) = a2 + b2;
    *(f4*)(go + mb + 48) = a3 + b3;
}

// ---------------- GRU v8: in-wave lane-deduplicated update, 1 barrier/step ----------------
// Wave w owns h rows [w*32, w*32+32): r tiles @ w*32, z @ 256+w*32, n @ 512+w*32.
// After MFMA, lane (quad,l16) selects its single (c=l16>>2&1, r=l16&3) D value via cndmask,
// does ONE gate update with per-lane gi/rowscale/bias, and l16<8 lanes scatter h to the
// ping-pong f16/i8 buffers. No ghs round-trip; no redundant update issue (R7's bug).
__global__ void __launch_bounds__(512) k_gru(
                      const signed char* __restrict__ Wq, const float* __restrict__ rowscale,
                      const _Float16* __restrict__ Whhh, const float* __restrict__ bhh,
                      const float* __restrict__ gi, const float* __restrict__ h0,
                      const float* __restrict__ tv,
                      const float* __restrict__ gateW, const float* __restrict__ gateU,
                      const float* __restrict__ gateb,
                      const float* __restrict__ outW, const float* __restrict__ outb,
                      float* __restrict__ out) {
    __shared__ __align__(16) _Float16 hbuf[2][HD];    // ping-pong h (f16)
    __shared__ __align__(16) signed char qbuf[2][HD]; // ping-pong h (i8, scale SH/127)
    __shared__ float hts[HD];
    __shared__ float sgs[512];
    __shared__ float vvs[HD];
    __shared__ float lg[8];

    int tid = threadIdx.x;
    int lane = tid & 63, w = tid >> 6, quad = lane >> 4, l16 = lane & 15;

    // i8 fragments: r tiles rows w*32+c*16, z tiles rows 256+w*32+c*16
    i4 far_[2][4], faz[2][4];
#pragma unroll
    for (int c = 0; c < 2; ++c) {
        const signed char* qr_ = Wq + (long)(w * 32 + c * 16 + l16) * HD;
        const signed char* qz_ = Wq + (long)(256 + w * 32 + c * 16 + l16) * HD;
#pragma unroll
        for (int kc = 0; kc < 4; ++kc) {
            far_[c][kc] = *(const i4*)(qr_ + kc * 64 + quad * 16);
            faz[c][kc] = *(const i4*)(qz_ + kc * 64 + quad * 16);
        }
    }
    // f16 fragments: n tiles rows 512+w*32+c*16
    uint4 fn[2][8];
#pragma unroll
    for (int c = 0; c < 2; ++c) {
        const _Float16* nb = Whhh + (long)(512 + w * 32 + c * 16 + l16) * HD;
#pragma unroll
        for (int kc = 0; kc < 8; ++kc)
            fn[c][kc] = *(const uint4*)(nb + kc * 32 + quad * 8);
    }

    // per-lane ownership: h index j = w*32 + sc*16 + quad*4 + sr  (l16<8 unique, l16>=8 dup)
    int sc = (l16 >> 2) & 1;
    int sr = l16 & 3;
    int j = w * 32 + sc * 16 + quad * 4 + sr;
    bool b2 = (sr & 2) != 0, b1 = (sr & 1) != 0, bc = (sc != 0);
    bool owner = (l16 < 8);

    float rs_r = rowscale[j];
    float rs_z = rowscale[256 + j];
    float bn_l = bhh[512 + j];

    float hv = h0[j];
    if (owner) {
        hbuf[0][j] = (_Float16)hv;
        float hc = fminf(fmaxf(hv, -SH), SH);
        qbuf[0][j] = (signed char)(int)rintf(hc * (127.f / SH));
    }
    __syncthreads();

    const float* gbase = gi + j;
    for (int t = 0; t < NS; ++t) {
        int p = t & 1;
        // per-lane gi loads (latency hidden under MFMA)
        const float* g = gbase + (long)t * TH;
        float gr_l = g[0], gz_l = g[256], gn_l = g[512];

        i4 qr[2], qz[2];
        f4 an[2];
#pragma unroll
        for (int c = 0; c < 2; ++c) { qr[c] = (i4){0,0,0,0}; qz[c] = (i4){0,0,0,0}; an[c] = (f4){0,0,0,0}; }
#pragma unroll
        for (int kc = 0; kc < 4; ++kc) {
            i4 b = *(const i4*)&qbuf[p][kc * 64 + quad * 16];
            qr[0] = __builtin_amdgcn_mfma_i32_16x16x64_i8(far_[0][kc], b, qr[0], 0, 0, 0);
            qr[1] = __builtin_amdgcn_mfma_i32_16x16x64_i8(far_[1][kc], b, qr[1], 0, 0, 0);
            qz[0] = __builtin_amdgcn_mfma_i32_16x16x64_i8(faz[0][kc], b, qz[0], 0, 0, 0);
            qz[1] = __builtin_amdgcn_mfma_i32_16x16x64_i8(faz[1][kc], b, qz[1], 0, 0, 0);
        }
#pragma unroll
        for (int kc = 0; kc < 8; ++kc) {
            half8 b = __builtin_bit_cast(half8, *(const uint4*)&hbuf[p][kc * 32 + quad * 8]);
            an[0] = __builtin_amdgcn_mfma_f32_16x16x32_f16(__builtin_bit_cast(half8, fn[0][kc]), b, an[0], 0, 0, 0);
            an[1] = __builtin_amdgcn_mfma_f32_16x16x32_f16(__builtin_bit_cast(half8, fn[1][kc]), b, an[1], 0, 0, 0);
        }
        // lane-select the (sc, sr) value from the 8 replicated D values
        int ra0 = bc ? qr[1][0] : qr[0][0], ra1 = bc ? qr[1][1] : qr[0][1];
        int ra2 = bc ? qr[1][2] : qr[0][2], ra3 = bc ? qr[1][3] : qr[0][3];
        int rt0 = b2 ? ra2 : ra0, rt1 = b2 ? ra3 : ra1;
        int qrv = b1 ? rt1 : rt0;
        int za0 = bc ? qz[1][0] : qz[0][0], za1 = bc ? qz[1][1] : qz[0][1];
        int za2 = bc ? qz[1][2] : qz[0][2], za3 = bc ? qz[1][3] : qz[0][3];
        int zt0 = b2 ? za2 : za0, zt1 = b2 ? za3 : za1;
        int qzv = b1 ? zt1 : zt0;
        float na0 = bc ? an[1][0] : an[0][0], na1 = bc ? an[1][1] : an[0][1];
        float na2 = bc ? an[1][2] : an[0][2], na3 = bc ? an[1][3] : an[0][3];
        float nt0 = b2 ? na2 : na0, nt1 = b2 ? na3 : na1;
        float anv = b1 ? nt1 : nt0;
        // single gate update per lane
        float rv = sigm(gr_l + (float)qrv * rs_r);
        float zv = sigm(gz_l + (float)qzv * rs_z);
        float nv = tanh_(gn_l + rv * (anv + bn_l));
        hv = (1.f - zv) * nv + zv * hv;
        if (owner) {
            hbuf[p ^ 1][j] = (_Float16)hv;
            float hc = fminf(fmaxf(hv, -SH), SH);
            qbuf[p ^ 1][j] = (signed char)(int)rintf(hc * (127.f / SH));
        }
        __syncthreads();
    }

    // head
    if (owner) hts[j] = hv;
    __syncthreads();
    {
        float s = gateb[tid];
        for (int k = 0; k < HD; ++k)
            s += gateW[tid * HD + k] * hts[k] + gateU[tid * HD + k] * tv[k];
        sgs[tid] = sigm(s);
    }
    __syncthreads();
    if (tid < HD) vvs[tid] = tanh_(sgs[tid] * hts[tid] + sgs[256 + tid] * tv[tid]);
    __syncthreads();
    if (tid < 5) {
        float s = outb[tid];
        for (int k = 0; k < HD; ++k) s += outW[tid * HD + k] * vvs[k];
        lg[tid] = s;
    }
    __syncthreads();
    if (tid == 0) {
        float m = lg[0];
        for (int i = 1; i < 5; ++i) m = fmaxf(m, lg[i]);
        float e[5], sum = 0.f;
        for (int i = 0; i < 5; ++i) { e[i] = __expf(lg[i] - m); sum += e[i]; }
        for (int i = 0; i < 5; ++i) out[i] = e[i] / sum;
    }
}

extern "C" void kernel_launch(void* const* d_in, const int* in_sizes, int n_in,
                              void* d_out, int out_size, void* d_ws, size_t ws_size,
                              hipStream_t stream) {
    (void)in_sizes; (void)n_in; (void)out_size; (void)ws_size;
    const int* sIdx = (const int*)d_in[0];
    const int* depT = (const int*)d_in[1];
    const float* DT = (const float*)d_in[2];
    const float* h0 = (const float*)d_in[3];
    const float* emb = (const float*)d_in[4];
    const float* q = (const float*)d_in[5];
    const float* W = (const float*)d_in[6];
    const float* U = (const float*)d_in[7];
    const float* Dm = (const float*)d_in[8];
    const float* b = (const float*)d_in[9];
    const float* Wih = (const float*)d_in[10];
    const float* Whh = (const float*)d_in[11];
    const float* bih = (const float*)d_in[12];
    const float* bhh = (const float*)d_in[13];
    const float* gateW = (const float*)d_in[14];
    const float* gateU = (const float*)d_in[15];
    const float* gateb = (const float*)d_in[16];
    const float* mlpW = (const float*)d_in[17];
    const float* mlpb = (const float*)d_in[18];
    const float* outW = (const float*)d_in[19];
    const float* outb = (const float*)d_in[20];

    char* ws = (char*)d_ws;
    unsigned short* Wb = (unsigned short*)ws;   ws += 768 * 320 * 2;
    _Float16* Uh = (_Float16*)ws;               ws += 768 * 256 * 2;
    _Float16* Wihh = (_Float16*)ws;             ws += 768 * 256 * 2;
    _Float16* Whhh = (_Float16*)ws;             ws += 768 * 256 * 2;
    signed char* Wq = (signed char*)ws;         ws += 512 * 256;
    float* rowscale = (float*)ws;               ws += 512 * 4;
    float* bias2 = (float*)ws;                  ws += 768 * 4;
    float* Dq = (float*)ws;                     ws += 10 * 768 * 4;
    float* tv = (float*)ws;                     ws += 1024;
    ws = (char*)d_ws + ((((size_t)(ws - (char*)d_ws)) + 4095) & ~(size_t)4095);
    unsigned short* pre = (unsigned short*)ws;  ws += (size_t)65536 * 768 * 2;
    float* gi = (float*)ws;                     ws += (size_t)1024 * 768 * 4;

    k_prep<<<dim3(799), dim3(256), 0, stream>>>(W, U, Wih, Whh, q, Dm, DT, mlpW, mlpb,
                                                bih, bhh,
                                                Wb, Uh, Wihh, Whhh, Wq, rowscale, bias2, Dq, tv);
    k_phaseB<<<dim3(2048), dim3(256), 0, stream>>>(sIdx, depT, emb, Wb, Dq, b, pre);
    k_phaseC<<<dim3(64), dim3(768), 0, stream>>>(pre, Uh, Wihh, bias2, gi);
    k_gru<<<dim3(1), dim3(512), 0, stream>>>(Wq, rowscale, Whhh, bhh, gi, h0, tv,
                                             gateW, gateU, gateb, outW, outb, (float*)d_out);
}

// Round 9
// 1313.614 us; speedup vs baseline: 1.6248x; 1.0989x over previous
//
#include <hip/hip_runtime.h>

typedef short short8 __attribute__((ext_vector_type(8)));
typedef float f4 __attribute__((ext_vector_type(4)));
typedef int i4 __attribute__((ext_vector_type(4)));
typedef _Float16 half8 __attribute__((ext_vector_type(8)));
typedef _Float16 h2 __attribute__((ext_vector_type(2)));

#define HD 256
#define ED 300
#define EP 320
#define TH 768
#define NS 1024
#define LW 64
#define SH 4.5f

__device__ __forceinline__ unsigned short f2bf(float f) {
    unsigned int u = __float_as_uint(f);
    u = (u + 0x7FFFu + ((u >> 16) & 1u)) >> 16;
    return (unsigned short)u;
}
__device__ __forceinline__ float bf2f(unsigned short s) {
    return __uint_as_float(((unsigned int)s) << 16);
}
__device__ __forceinline__ float sigm(float x) {
    return __builtin_amdgcn_rcpf(1.f + __expf(-x));
}
__device__ __forceinline__ float tanh_(float x) {
    x = fminf(fmaxf(x, -15.f), 15.f);
    return 1.f - 2.f * __builtin_amdgcn_rcpf(1.f + __expf(2.f * x));
}
__device__ __forceinline__ unsigned int pack_h2(float a, float b) {
    h2 p; p.x = (_Float16)a; p.y = (_Float16)b;
    return __builtin_bit_cast(unsigned int, p);
}

__device__ __forceinline__ void load8bf(const unsigned short* p, float* o) {
    uint4 a = *(const uint4*)p;
    o[0] = bf2f((unsigned short)(a.x & 0xffff)); o[1] = bf2f((unsigned short)(a.x >> 16));
    o[2] = bf2f((unsigned short)(a.y & 0xffff)); o[3] = bf2f((unsigned short)(a.y >> 16));
    o[4] = bf2f((unsigned short)(a.z & 0xffff)); o[5] = bf2f((unsigned short)(a.z >> 16));
    o[6] = bf2f((unsigned short)(a.w & 0xffff)); o[7] = bf2f((unsigned short)(a.w >> 16));
}
__device__ __forceinline__ void ubf4(uint2 a, float* o) {
    o[0] = bf2f((unsigned short)(a.x & 0xffff)); o[1] = bf2f((unsigned short)(a.x >> 16));
    o[2] = bf2f((unsigned short)(a.y & 0xffff)); o[3] = bf2f((unsigned short)(a.y >> 16));
}

// ---------------- prep: weight conversions, i8 quantization (ALL 768 Whh rows), Dq, topic ----------------
__global__ void k_prep(const float* __restrict__ W, const float* __restrict__ U,
                       const float* __restrict__ Wih, const float* __restrict__ Whh,
                       const float* __restrict__ q, const float* __restrict__ Dm,
                       const float* __restrict__ DT, const float* __restrict__ mlpW,
                       const float* __restrict__ mlpb,
                       const float* __restrict__ bih, const float* __restrict__ bhh,
                       unsigned short* __restrict__ Wb, _Float16* __restrict__ Uh,
                       _Float16* __restrict__ Wihh,
                       signed char* __restrict__ Wq, float* __restrict__ rowscale,
                       float* __restrict__ bias2,
                       float* __restrict__ Dq, float* __restrict__ tv) {
    __shared__ float smax[4];
    int bid = blockIdx.x, tid = threadIdx.x;
    if (bid < 768) {
        int r = bid;
        for (int j = tid; j < EP; j += 256)
            Wb[r * EP + j] = (j < ED) ? f2bf(W[r * ED + j]) : (unsigned short)0;
        float whv = Whh[r * HD + tid];
        for (int j = tid; j < HD; j += 256) {
            Uh[r * HD + j] = (_Float16)U[r * HD + j];
            Wihh[r * HD + j] = (_Float16)Wih[r * HD + j];
        }
        // per-row i8 quantization of ALL Whh rows
        float v = fabsf(whv);
        for (int o = 32; o; o >>= 1) v = fmaxf(v, __shfl_xor(v, o));
        if ((tid & 63) == 0) smax[tid >> 6] = v;
        __syncthreads();
        float am = fmaxf(fmaxf(smax[0], smax[1]), fmaxf(smax[2], smax[3]));
        float inv = (am > 0.f) ? 127.f / am : 0.f;
        int qi = (int)rintf(whv * inv);
        qi = max(-127, min(127, qi));
        Wq[r * HD + tid] = (signed char)qi;
        if (tid == 0) rowscale[r] = (am / 127.f) * (SH / 127.f);
    } else if (bid < 798) {
        int idx = bid - 768;
        int d = idx / 3, part = idx - d * 3;
        int n = part * 256 + tid;
        float s = 0.f;
        for (int h = 0; h < HD; ++h) s += Dm[n * HD + h] * q[d * HD + h];
        Dq[d * TH + n] = s;
    } else {
        if (tid < HD) {
            float s = 0.f;
            for (int k = 0; k < 100; ++k) s += mlpW[tid * 100 + k] * DT[k];
            tv[tid] = tanh_(s + mlpb[tid]);
        }
        for (int r = tid; r < TH; r += 256)
            bias2[r] = bih[r] + ((r < 512) ? bhh[r] : 0.f);
    }
}

// ---------------- phase B v2: x staged once in LDS as bf16; K-loop = ds_read + MFMA only ----------------
#define XP 328   // padded LDS row stride (elements); 328*2B/4 = 164 dwords, %32=4 -> 2-way alias (free)
__launch_bounds__(256, 2)
__global__ void k_phaseB(const int* __restrict__ sIdx, const int* __restrict__ depT,
                         const float* __restrict__ emb, const unsigned short* __restrict__ Wb,
                         const float* __restrict__ Dq, const float* __restrict__ bias,
                         unsigned short* __restrict__ pre) {
    __shared__ float dq_s[10 * 772];
    __shared__ float b_s[TH];
    __shared__ int dep_s[32];
    __shared__ int idx_s[32];
    __shared__ __align__(16) unsigned short xbf[32 * XP];
    int tid = threadIdx.x;
    int c0 = blockIdx.x * 32;
    for (int i = tid; i < 10 * 768; i += 256) {
        int d = i / 768, n = i - d * 768;
        dq_s[d * 772 + n] = Dq[i];
    }
    for (int i = tid; i < TH; i += 256) b_s[i] = bias[i];
    if (tid < 32) {
        int m = c0 + tid;
        idx_s[tid] = sIdx[m];
        int l = m & 63, s = m >> 6;
        dep_s[tid] = (l == 63) ? 9 : depT[s * 63 + l];
    }
    __syncthreads();
    // stage 32 gathered x rows as bf16 (coalesced within a row)
    for (int i = tid; i < 32 * EP; i += 256) {
        int row = i / EP, col = i - row * EP;
        unsigned short v = 0;
        if (col < ED) v = f2bf(emb[(long)idx_s[row] * ED + col]);
        xbf[row * XP + col] = v;
    }
    __syncthreads();

    int lane = tid & 63;
    int w = tid >> 6;
    int quad = lane >> 4, l16 = lane & 15;

    f4 acc[2][12];
#pragma unroll
    for (int cs = 0; cs < 2; ++cs)
#pragma unroll
        for (int ms = 0; ms < 12; ++ms) acc[cs][ms] = (f4){0.f, 0.f, 0.f, 0.f};

    const unsigned short* wbase = Wb + (w * 192 + l16) * EP;

#pragma unroll
    for (int kt = 0; kt < 10; ++kt) {
        int k0 = kt * 32 + quad * 8;
        short8 bf0 = *(const short8*)&xbf[l16 * XP + k0];
        short8 bf1 = *(const short8*)&xbf[(16 + l16) * XP + k0];
#pragma unroll
        for (int ms = 0; ms < 12; ++ms) {
            short8 af = *(const short8*)(wbase + ms * 16 * EP + k0);
            acc[0][ms] = __builtin_amdgcn_mfma_f32_16x16x32_bf16(af, bf0, acc[0][ms], 0, 0, 0);
            acc[1][ms] = __builtin_amdgcn_mfma_f32_16x16x32_bf16(af, bf1, acc[1][ms], 0, 0, 0);
        }
    }

#pragma unroll
    for (int cs = 0; cs < 2; ++cs) {
        int xr = c0 + cs * 16 + l16;
        int dep = dep_s[cs * 16 + l16];
        unsigned short* prow = pre + (long)xr * TH;
#pragma unroll
        for (int ms = 0; ms < 12; ++ms) {
            int ncol = w * 192 + ms * 16 + quad * 4;
            f4 dq4 = *(const f4*)&dq_s[dep * 772 + ncol];
            f4 b4 = *(const f4*)&b_s[ncol];
            unsigned int lo = (unsigned int)f2bf(acc[cs][ms][0] + dq4[0] + b4[0]) |
                              ((unsigned int)f2bf(acc[cs][ms][1] + dq4[1] + b4[1]) << 16);
            unsigned int hi = (unsigned int)f2bf(acc[cs][ms][2] + dq4[2] + b4[2]) |
                              ((unsigned int)f2bf(acc[cs][ms][3] + dq4[3] + b4[3]) << 16);
            uint2 v; v.x = lo; v.y = hi;
            *(uint2*)(prow + ncol) = v;
        }
    }
}

// ---------------- phase C: U AGPR-resident MFMA, 16 sentences/WG, pre-loads hoisted ----------------
__global__ void __launch_bounds__(768) k_phaseC(
                         const unsigned short* __restrict__ pre,
                         const _Float16* __restrict__ Uh,
                         const _Float16* __restrict__ Wihh,
                         const float* __restrict__ bias2,
                         float* __restrict__ gi) {
    __shared__ __align__(16) uint4 hfr[512];
    __shared__ __align__(16) float tot[16 * 772];
    int tid = threadIdx.x;
    int lane = tid & 63, w = tid >> 6, quad = lane >> 4, l16 = lane & 15;
    int s0 = blockIdx.x * 16;

    uint4 frag[32];
    {
        const _Float16* base = Uh + (w * 64 + l16) * HD;
#pragma unroll
        for (int t = 0; t < 4; ++t)
#pragma unroll
            for (int kt = 0; kt < 8; ++kt)
                frag[t * 8 + kt] = *(const uint4*)(base + t * 16 * HD + kt * 32 + quad * 8);
    }

    int us = tid >> 5;
    int jg = tid & 31;
    int j0 = jg * 8;
    int hcell = (j0 >> 5) * 64 + 16 * ((j0 >> 3) & 3) + us;
    uint4 hcp;

    if (tid < 512) {
        const unsigned short* prow = pre + ((long)(s0 + us) * LW + 63) * TH;
        float iv[8], uv[8], hcv[8];
        load8bf(prow + 256 + j0, iv);
        load8bf(prow + 512 + j0, uv);
#pragma unroll
        for (int r = 0; r < 8; ++r) hcv[r] = tanh_(sigm(iv[r]) * tanh_(uv[r]));
        hcp.x = pack_h2(hcv[0], hcv[1]); hcp.y = pack_h2(hcv[2], hcv[3]);
        hcp.z = pack_h2(hcv[4], hcv[5]); hcp.w = pack_h2(hcv[6], hcv[7]);
        hfr[hcell] = hcp;
    }
    __syncthreads();

    int mb = w * 64 + quad * 4;

    for (int step = 0; step < 63; ++step) {
        int l = 62 - step;
        uint2 praw[6];
        if (tid < 512) {
            const unsigned short* prow = pre + ((long)(s0 + us) * LW + l) * TH;
#pragma unroll
            for (int g = 0; g < 3; ++g) {
                praw[2 * g]     = *(const uint2*)(prow + g * 256 + j0);
                praw[2 * g + 1] = *(const uint2*)(prow + g * 256 + j0 + 4);
            }
        }
        f4 a0 = (f4){0,0,0,0}, a1 = (f4){0,0,0,0}, a2 = (f4){0,0,0,0}, a3 = (f4){0,0,0,0};
#pragma unroll
        for (int kt = 0; kt < 8; ++kt) {
            half8 b = __builtin_bit_cast(half8, hfr[kt * 64 + lane]);
            a0 = __builtin_amdgcn_mfma_f32_16x16x32_f16(__builtin_bit_cast(half8, frag[kt]), b, a0, 0, 0, 0);
            a1 = __builtin_amdgcn_mfma_f32_16x16x32_f16(__builtin_bit_cast(half8, frag[8 + kt]), b, a1, 0, 0, 0);
            a2 = __builtin_amdgcn_mfma_f32_16x16x32_f16(__builtin_bit_cast(half8, frag[16 + kt]), b, a2, 0, 0, 0);
            a3 = __builtin_amdgcn_mfma_f32_16x16x32_f16(__builtin_bit_cast(half8, frag[24 + kt]), b, a3, 0, 0, 0);
        }
        float* tr = tot + l16 * 772;
        *(f4*)&tr[mb] = a0;
        *(f4*)&tr[mb + 16] = a1;
        *(f4*)&tr[mb + 32] = a2;
        *(f4*)&tr[mb + 48] = a3;
        __syncthreads();
        if (tid < 512) {
            const float* ts = tot + us * 772;
            float hcv[8];
            h2 px = __builtin_bit_cast(h2, hcp.x); h2 py = __builtin_bit_cast(h2, hcp.y);
            h2 pz = __builtin_bit_cast(h2, hcp.z); h2 pw = __builtin_bit_cast(h2, hcp.w);
            hcv[0] = (float)px.x; hcv[1] = (float)px.y; hcv[2] = (float)py.x; hcv[3] = (float)py.y;
            hcv[4] = (float)pz.x; hcv[5] = (float)pz.y; hcv[6] = (float)pw.x; hcv[7] = (float)pw.y;
#pragma unroll
            for (int hf = 0; hf < 2; ++hf) {
                int jb = j0 + hf * 4;
                float pf[4], pi_[4], pu[4];
                ubf4(praw[hf], pf);
                ubf4(praw[2 + hf], pi_);
                ubf4(praw[4 + hf], pu);
                f4 tf = *(const f4*)&ts[jb];
                f4 ti = *(const f4*)&ts[256 + jb];
                f4 tu = *(const f4*)&ts[512 + jb];
#pragma unroll
                for (int r = 0; r < 4; ++r) {
                    float ff = tf[r] + pf[r];
                    float ii = ti[r] + pi_[r];
                    float uu = tu[r] + pu[r];
                    hcv[hf * 4 + r] = tanh_(sigm(ii) * tanh_(uu) + sigm(ff) * hcv[hf * 4 + r]);
                }
            }
            hcp.x = pack_h2(hcv[0], hcv[1]); hcp.y = pack_h2(hcv[2], hcv[3]);
            hcp.z = pack_h2(hcv[4], hcv[5]); hcp.w = pack_h2(hcv[6], hcv[7]);
            hfr[hcell] = hcp;
        }
        __syncthreads();
    }

    {
        const _Float16* base = Wihh + (w * 64 + l16) * HD;
#pragma unroll
        for (int t = 0; t < 4; ++t)
#pragma unroll
            for (int kt = 0; kt < 8; ++kt)
                frag[t * 8 + kt] = *(const uint4*)(base + t * 16 * HD + kt * 32 + quad * 8);
    }
    f4 a0 = (f4){0,0,0,0}, a1 = (f4){0,0,0,0}, a2 = (f4){0,0,0,0}, a3 = (f4){0,0,0,0};
#pragma unroll
    for (int kt = 0; kt < 8; ++kt) {
        half8 b = __builtin_bit_cast(half8, hfr[kt * 64 + lane]);
        a0 = __builtin_amdgcn_mfma_f32_16x16x32_f16(__builtin_bit_cast(half8, frag[kt]), b, a0, 0, 0, 0);
        a1 = __builtin_amdgcn_mfma_f32_16x16x32_f16(__builtin_bit_cast(half8, frag[8 + kt]), b, a1, 0, 0, 0);
        a2 = __builtin_amdgcn_mfma_f32_16x16x32_f16(__builtin_bit_cast(half8, frag[16 + kt]), b, a2, 0, 0, 0);
        a3 = __builtin_amdgcn_mfma_f32_16x16x32_f16(__builtin_bit_cast(half8, frag[24 + kt]), b, a3, 0, 0, 0);
    }
    float* go = gi + (long)(s0 + l16) * TH;
    f4 b0 = *(const f4*)(bias2 + mb);
    f4 b1 = *(const f4*)(bias2 + mb + 16);
    f4 b2 = *(const f4*)(bias2 + mb + 32);
    f4 b3 = *(const f4*)(bias2 + mb + 48);
    *(f4*)(go + mb) = a0 + b0;
    *(f4*)(go + mb + 16) = a1 + b1;
    *(f4*)(go + mb + 32) = a2 + b2;
    *(f4*)(go + mb + 48) = a3 + b3;
}

// ---------------- GRU v9: all-i8 matvec (r,z,n), lane-dedup update, 1 barrier/step ----------------
// Wave w owns h rows [w*32, w*32+32). 24 i8 MFMA/wave (was 16 i8 + 16 f16).
// h kept exact in f32 per-lane; only the MFMA input (qbuf, i8) is quantized.
__global__ void __launch_bounds__(512) k_gru(
                      const signed char* __restrict__ Wq, const float* __restrict__ rowscale,
                      const float* __restrict__ bhh,
                      const float* __restrict__ gi, const float* __restrict__ h0,
                      const float* __restrict__ tv,
                      const float* __restrict__ gateW, const float* __restrict__ gateU,
                      const float* __restrict__ gateb,
                      const float* __restrict__ outW, const float* __restrict__ outb,
                      float* __restrict__ out) {
    __shared__ __align__(16) signed char qbuf[2][HD]; // ping-pong h (i8, scale SH/127)
    __shared__ float hts[HD];
    __shared__ float sgs[512];
    __shared__ float vvs[HD];
    __shared__ float lg[8];

    int tid = threadIdx.x;
    int lane = tid & 63, w = tid >> 6, quad = lane >> 4, l16 = lane & 15;

    // i8 fragments: r tiles rows w*32+c*16, z tiles 256+..., n tiles 512+...
    i4 far_[2][4], faz[2][4], fan[2][4];
#pragma unroll
    for (int c = 0; c < 2; ++c) {
        const signed char* qr_ = Wq + (long)(w * 32 + c * 16 + l16) * HD;
        const signed char* qz_ = Wq + (long)(256 + w * 32 + c * 16 + l16) * HD;
        const signed char* qn_ = Wq + (long)(512 + w * 32 + c * 16 + l16) * HD;
#pragma unroll
        for (int kc = 0; kc < 4; ++kc) {
            far_[c][kc] = *(const i4*)(qr_ + kc * 64 + quad * 16);
            faz[c][kc] = *(const i4*)(qz_ + kc * 64 + quad * 16);
            fan[c][kc] = *(const i4*)(qn_ + kc * 64 + quad * 16);
        }
    }

    // per-lane ownership: h index j = w*32 + sc*16 + quad*4 + sr  (l16<8 unique)
    int sc = (l16 >> 2) & 1;
    int sr = l16 & 3;
    int j = w * 32 + sc * 16 + quad * 4 + sr;
    bool b2 = (sr & 2) != 0, b1 = (sr & 1) != 0, bc = (sc != 0);
    bool owner = (l16 < 8);

    float rs_r = rowscale[j];
    float rs_z = rowscale[256 + j];
    float rs_n = rowscale[512 + j];
    float bn_l = bhh[512 + j];

    float hv = h0[j];
    if (owner) {
        float hc = fminf(fmaxf(hv, -SH), SH);
        qbuf[0][j] = (signed char)(int)rintf(hc * (127.f / SH));
    }
    __syncthreads();

    const float* gbase = gi + j;
    for (int t = 0; t < NS; ++t) {
        int p = t & 1;
        const float* g = gbase + (long)t * TH;
        float gr_l = g[0], gz_l = g[256], gn_l = g[512];

        i4 qr[2], qz[2], qn[2];
#pragma unroll
        for (int c = 0; c < 2; ++c) { qr[c] = (i4){0,0,0,0}; qz[c] = (i4){0,0,0,0}; qn[c] = (i4){0,0,0,0}; }
#pragma unroll
        for (int kc = 0; kc < 4; ++kc) {
            i4 b = *(const i4*)&qbuf[p][kc * 64 + quad * 16];
            qr[0] = __builtin_amdgcn_mfma_i32_16x16x64_i8(far_[0][kc], b, qr[0], 0, 0, 0);
            qr[1] = __builtin_amdgcn_mfma_i32_16x16x64_i8(far_[1][kc], b, qr[1], 0, 0, 0);
            qz[0] = __builtin_amdgcn_mfma_i32_16x16x64_i8(faz[0][kc], b, qz[0], 0, 0, 0);
            qz[1] = __builtin_amdgcn_mfma_i32_16x16x64_i8(faz[1][kc], b, qz[1], 0, 0, 0);
            qn[0] = __builtin_amdgcn_mfma_i32_16x16x64_i8(fan[0][kc], b, qn[0], 0, 0, 0);
            qn[1] = __builtin_amdgcn_mfma_i32_16x16x64_i8(fan[1][kc], b, qn[1], 0, 0, 0);
        }
        // lane-select the (sc, sr) value from the 8 replicated D values
        int ra0 = bc ? qr[1][0] : qr[0][0], ra1 = bc ? qr[1][1] : qr[0][1];
        int ra2 = bc ? qr[1][2] : qr[0][2], ra3 = bc ? qr[1][3] : qr[0][3];
        int rt0 = b2 ? ra2 : ra0, rt1 = b2 ? ra3 : ra1;
        int qrv = b1 ? rt1 : rt0;
        int za0 = bc ? qz[1][0] : qz[0][0], za1 = bc ? qz[1][1] : qz[0][1];
        int za2 = bc ? qz[1][2] : qz[0][2], za3 = bc ? qz[1][3] : qz[0][3];
        int zt0 = b2 ? za2 : za0, zt1 = b2 ? za3 : za1;
        int qzv = b1 ? zt1 : zt0;
        int na0 = bc ? qn[1][0] : qn[0][0], na1 = bc ? qn[1][1] : qn[0][1];
        int na2 = bc ? qn[1][2] : qn[0][2], na3 = bc ? qn[1][3] : qn[0][3];
        int nt0 = b2 ? na2 : na0, nt1 = b2 ? na3 : na1;
        int qnv = b1 ? nt1 : nt0;
        // single gate update per lane
        float rv = sigm(gr_l + (float)qrv * rs_r);
        float zv = sigm(gz_l + (float)qzv * rs_z);
        float nv = tanh_(gn_l + rv * ((float)qnv * rs_n + bn_l));
        hv = (1.f - zv) * nv + zv * hv;
        if (owner) {
            float hc = fminf(fmaxf(hv, -SH), SH);
            qbuf[p ^ 1][j] = (signed char)(int)rintf(hc * (127.f / SH));
        }
        __syncthreads();
    }

    // head
    if (owner) hts[j] = hv;
    __syncthreads();
    {
        float s = gateb[tid];
        for (int k = 0; k < HD; ++k)
            s += gateW[tid * HD + k] * hts[k] + gateU[tid * HD + k] * tv[k];
        sgs[tid] = sigm(s);
    }
    __syncthreads();
    if (tid < HD) vvs[tid] = tanh_(sgs[tid] * hts[tid] + sgs[256 + tid] * tv[tid]);
    __syncthreads();
    if (tid < 5) {
        float s = outb[tid];
        for (int k = 0; k < HD; ++k) s += outW[tid * HD + k] * vvs[k];
        lg[tid] = s;
    }
    __syncthreads();
    if (tid == 0) {
        float m = lg[0];
        for (int i = 1; i < 5; ++i) m = fmaxf(m, lg[i]);
        float e[5], sum = 0.f;
        for (int i = 0; i < 5; ++i) { e[i] = __expf(lg[i] - m); sum += e[i]; }
        for (int i = 0; i < 5; ++i) out[i] = e[i] / sum;
    }
}

extern "C" void kernel_launch(void* const* d_in, const int* in_sizes, int n_in,
                              void* d_out, int out_size, void* d_ws, size_t ws_size,
                              hipStream_t stream) {
    (void)in_sizes; (void)n_in; (void)out_size; (void)ws_size;
    const int* sIdx = (const int*)d_in[0];
    const int* depT = (const int*)d_in[1];
    const float* DT = (const float*)d_in[2];
    const float* h0 = (const float*)d_in[3];
    const float* emb = (const float*)d_in[4];
    const float* q = (const float*)d_in[5];
    const float* W = (const float*)d_in[6];
    const float* U = (const float*)d_in[7];
    const float* Dm = (const float*)d_in[8];
    const float* b = (const float*)d_in[9];
    const float* Wih = (const float*)d_in[10];
    const float* Whh = (const float*)d_in[11];
    const float* bih = (const float*)d_in[12];
    const float* bhh = (const float*)d_in[13];
    const float* gateW = (const float*)d_in[14];
    const float* gateU = (const float*)d_in[15];
    const float* gateb = (const float*)d_in[16];
    const float* mlpW = (const float*)d_in[17];
    const float* mlpb = (const float*)d_in[18];
    const float* outW = (const float*)d_in[19];
    const float* outb = (const float*)d_in[20];

    char* ws = (char*)d_ws;
    unsigned short* Wb = (unsigned short*)ws;   ws += 768 * 320 * 2;
    _Float16* Uh = (_Float16*)ws;               ws += 768 * 256 * 2;
    _Float16* Wihh = (_Float16*)ws;             ws += 768 * 256 * 2;
    signed char* Wq = (signed char*)ws;         ws += 768 * 256;
    float* rowscale = (float*)ws;               ws += 768 * 4;
    float* bias2 = (float*)ws;                  ws += 768 * 4;
    float* Dq = (float*)ws;                     ws += 10 * 768 * 4;
    float* tv = (float*)ws;                     ws += 1024;
    ws = (char*)d_ws + ((((size_t)(ws - (char*)d_ws)) + 4095) & ~(size_t)4095);
    unsigned short* pre = (unsigned short*)ws;  ws += (size_t)65536 * 768 * 2;
    float* gi = (float*)ws;                     ws += (size_t)1024 * 768 * 4;

    k_prep<<<dim3(799), dim3(256), 0, stream>>>(W, U, Wih, Whh, q, Dm, DT, mlpW, mlpb,
                                                bih, bhh,
                                                Wb, Uh, Wihh, Wq, rowscale, bias2, Dq, tv);
    k_phaseB<<<dim3(2048), dim3(256), 0, stream>>>(sIdx, depT, emb, Wb, Dq, b, pre);
    k_phaseC<<<dim3(64), dim3(768), 0, stream>>>(pre, Uh, Wihh, bias2, gi);
    k_gru<<<dim3(1), dim3(512), 0, stream>>>(Wq, rowscale, bhh, gi, h0, tv,
                                             gateW, gateU, gateb, outW, outb, (float*)d_out);
}